// Round 1
// baseline (820.881 us; speedup 1.0000x reference)
//
#include <hip/hip_runtime.h>

typedef unsigned int u32;
typedef unsigned short u16;

#define N_NODES 50000
#define N_EDGES 400000
#define IN_F 512
#define HID 512
#define OUT_F 256
#define N_CELL 1000
#define N_DIM 128
#define N_SEL 8192
#define N_C 1024
#define MPAD 50048  // 391*128, node count padded to 128-row GEMM tiles

typedef __bf16 bf16x8 __attribute__((ext_vector_type(8)));
typedef float f32x4 __attribute__((ext_vector_type(4)));

__device__ __forceinline__ u16 f2bf(float f) {
    u32 u = __builtin_bit_cast(u32, f);
    u32 r = (u + 0x7fffu + ((u >> 16) & 1u)) >> 16;  // RNE
    return (u16)r;
}
__device__ __forceinline__ float bf2f(u32 bits16) {
    return __builtin_bit_cast(float, bits16 << 16);
}

// ---------------- graph prep ----------------

__global__ void degrees_kernel(const int* __restrict__ src, const int* __restrict__ dst,
                               int* __restrict__ degO, int* __restrict__ degI) {
    int e = blockIdx.x * 256 + threadIdx.x;
    if (e < N_EDGES) {
        atomicAdd(&degO[src[e]], 1);
        atomicAdd(&degI[dst[e]], 1);
    }
}

// exclusive prefix sum of degI -> offs[0..N_NODES], single block, chunked
__global__ void scan_kernel(const int* __restrict__ deg, int* __restrict__ offs) {
    __shared__ int sh[1024];
    const int t = threadIdx.x;
    const int chunk = (N_NODES + 1023) >> 10;  // 49
    const int start = t * chunk;
    const int end = min(start + chunk, N_NODES);
    int sum = 0;
    for (int i = start; i < end; ++i) sum += deg[i];
    sh[t] = sum;
    __syncthreads();
    for (int off = 1; off < 1024; off <<= 1) {
        int v = (t >= off) ? sh[t - off] : 0;
        __syncthreads();
        sh[t] += v;
        __syncthreads();
    }
    int run = sh[t] - sum;  // exclusive prefix of this chunk
    for (int i = start; i < end; ++i) { offs[i] = run; run += deg[i]; }
    if (end == N_NODES) offs[N_NODES] = run;  // total = N_EDGES
}

__global__ void fill_csr_kernel(const int* __restrict__ src, const int* __restrict__ dst,
                                int* __restrict__ cursor, const int* __restrict__ offs,
                                int* __restrict__ csr) {
    int e = blockIdx.x * 256 + threadIdx.x;
    if (e < N_EDGES) {
        int d = dst[e];
        int slot = atomicAdd(&cursor[d], 1);
        csr[offs[d] + slot] = src[e];
    }
}

__global__ void norms_kernel(const int* __restrict__ degO, const int* __restrict__ degI,
                             float* __restrict__ ns, float* __restrict__ nd) {
    int i = blockIdx.x * 256 + threadIdx.x;
    if (i < N_NODES) {
        ns[i] = degO[i] > 0 ? rsqrtf((float)degO[i]) : 0.f;
        nd[i] = degI[i] > 0 ? rsqrtf((float)degI[i]) : 0.f;
    }
}

// ---------------- conversions ----------------

// src[K][N] fp32 -> dst[N][K] bf16 (weights, small)
__global__ void trans_bf16_kernel(const float* __restrict__ src, u16* __restrict__ dst,
                                  int K, int N) {
    int i = blockIdx.x * 256 + threadIdx.x;
    if (i >= K * N) return;
    int n = i / K, k = i % K;
    dst[i] = f2bf(src[k * N + n]);
}

// x fp32 [N_NODES][512] -> bf16 [MPAD][512], zero pad rows
__global__ void convert_x_kernel(const float* __restrict__ x, u16* __restrict__ xb) {
    int i = blockIdx.x * 256 + threadIdx.x;  // one per 4 elems; grid exact
    int base = i * 4;
    int m = base >> 9;
    ushort4 o;
    if (m < N_NODES) {
        float4 v = *(const float4*)(x + base);
        o.x = f2bf(v.x); o.y = f2bf(v.y); o.z = f2bf(v.z); o.w = f2bf(v.w);
    } else {
        o = make_ushort4(0, 0, 0, 0);
    }
    *(ushort4*)(xb + base) = o;
}

// eb[c][:] = bf16(emb[c_indices[c]][:])
__global__ void gather_emb_kernel(const float* __restrict__ emb, const int* __restrict__ cidx,
                                  u16* __restrict__ eb) {
    int c = blockIdx.x, f = threadIdx.x;
    eb[c * N_DIM + f] = f2bf(emb[(size_t)cidx[c] * N_DIM + f]);
}

// ---------------- MFMA GEMM (NT: A[M][K] bf16, B[N][K] bf16) ----------------
// C = A @ B^T ; optional A-row gather (aidx), row scale, col bias; bf16 or f32 out.
// 128x128 tile, BK=32, 4 waves each 64x64 via 4x4 of 16x16x32 MFMA.
__global__ __launch_bounds__(256, 2) void gemm_bf16_nt(
    const u16* __restrict__ A, const u16* __restrict__ B,
    const int* __restrict__ aidx,
    u16* __restrict__ Cb, float* __restrict__ Cf,
    const float* __restrict__ scale, int nScale,
    const float* __restrict__ bias,
    int N, int K) {
    __shared__ __align__(16) u16 As[128 * 40];  // row stride 40 elems = 80B (16B-aligned, 2-way banks)
    __shared__ __align__(16) u16 Bs[128 * 40];
    const int t = threadIdx.x;
    const int m0 = blockIdx.x * 128, n0 = blockIdx.y * 128;
    const int srow = t >> 1;            // staging row 0..127
    const int skk = (t & 1) << 4;       // staging k offset 0/16
    const int l = t & 63, w = t >> 6;
    const int wm = (w >> 1) << 6, wn = (w & 1) << 6;
    const int lr = l & 15, quad = l >> 4;

    int arow = m0 + srow;
    if (aidx) arow = aidx[arow];
    const u16* ga = A + (size_t)arow * K + skk;
    const u16* gb = B + (size_t)(n0 + srow) * K + skk;
    u16* la = &As[srow * 40 + skk];
    u16* lb = &Bs[srow * 40 + skk];

    f32x4 acc[4][4] = {};

    for (int ks = 0; ks < K; ks += 32) {
        uint4 a0 = *(const uint4*)(ga + ks);
        uint4 a1 = *(const uint4*)(ga + ks + 8);
        uint4 b0 = *(const uint4*)(gb + ks);
        uint4 b1 = *(const uint4*)(gb + ks + 8);
        *(uint4*)la = a0;
        *(uint4*)(la + 8) = a1;
        *(uint4*)lb = b0;
        *(uint4*)(lb + 8) = b1;
        __syncthreads();
        bf16x8 af[4], bg[4];
#pragma unroll
        for (int i = 0; i < 4; ++i)
            af[i] = *(const bf16x8*)&As[(wm + i * 16 + lr) * 40 + quad * 8];
#pragma unroll
        for (int j = 0; j < 4; ++j)
            bg[j] = *(const bf16x8*)&Bs[(wn + j * 16 + lr) * 40 + quad * 8];
#pragma unroll
        for (int i = 0; i < 4; ++i)
#pragma unroll
            for (int j = 0; j < 4; ++j)
                acc[i][j] = __builtin_amdgcn_mfma_f32_16x16x32_bf16(af[i], bg[j], acc[i][j], 0, 0, 0);
        __syncthreads();
    }

    // C/D layout (m89-verified): col = lane&15, row = quad*4 + reg
#pragma unroll
    for (int i = 0; i < 4; ++i) {
        int rbase = m0 + wm + i * 16 + quad * 4;
#pragma unroll
        for (int j = 0; j < 4; ++j) {
            int col = n0 + wn + j * 16 + lr;
            float bv = bias ? bias[col] : 0.f;
#pragma unroll
            for (int r = 0; r < 4; ++r) {
                int rg = rbase + r;
                float sc = scale ? (rg < nScale ? scale[rg] : 0.f) : 1.f;
                float v = acc[i][j][r] * sc + bv;
                if (Cb) Cb[(size_t)rg * N + col] = f2bf(v);
                else    Cf[(size_t)rg * N + col] = v;
            }
        }
    }
}

// ---------------- CSR aggregation: H[n] = relu(nd[n] * sum_{s in N(n)} T[s] + b) ----------------
template <int F>
__global__ __launch_bounds__(F / 2) void aggregate_kernel(
    const u16* __restrict__ T, const int* __restrict__ csr,
    const int* __restrict__ offs, const float* __restrict__ nd,
    const float* __restrict__ bias, u16* __restrict__ H) {
    const int node = blockIdx.x;
    const int t = threadIdx.x;  // F/2 threads, 2 feats each
    u32* __restrict__ Hrow = (u32*)H + (size_t)node * (F / 2);
    if (node >= N_NODES) { Hrow[t] = 0u; return; }
    const int s0 = offs[node], s1 = offs[node + 1];
    const u32* __restrict__ Tu = (const u32*)T;
    float a0 = 0.f, a1 = 0.f;
    for (int e = s0; e < s1; ++e) {
        int s = csr[e];
        u32 v = Tu[(size_t)s * (F / 2) + t];
        a0 += bf2f(v & 0xffffu);
        a1 += bf2f(v >> 16);
    }
    float ndv = nd[node];
    float r0 = fmaxf(fmaf(a0, ndv, bias[2 * t]), 0.f);
    float r1 = fmaxf(fmaf(a1, ndv, bias[2 * t + 1]), 0.f);
    Hrow[t] = (u32)f2bf(r0) | ((u32)f2bf(r1) << 16);
}

// ---------------- launch ----------------

extern "C" void kernel_launch(void* const* d_in, const int* in_sizes, int n_in,
                              void* d_out, int out_size, void* d_ws, size_t ws_size,
                              hipStream_t stream) {
    const float* x   = (const float*)d_in[0];
    const int*   src = (const int*)d_in[1];
    const int*   dst = (const int*)d_in[2];
    const int*   xidx= (const int*)d_in[3];
    const int*   cidx= (const int*)d_in[4];
    const float* W1  = (const float*)d_in[5];
    const float* b1  = (const float*)d_in[6];
    const float* W2  = (const float*)d_in[7];
    const float* b2  = (const float*)d_in[8];
    const float* W3  = (const float*)d_in[9];
    const float* b3  = (const float*)d_in[10];
    const float* Wp  = (const float*)d_in[11];
    const float* bp  = (const float*)d_in[12];
    const float* emb = (const float*)d_in[13];
    float* out = (float*)d_out;

    char* p = (char*)d_ws;
    auto alloc = [&](size_t bytes) {
        char* r = p;
        p += (bytes + 255) & ~(size_t)255;
        return r;
    };
    u16* T    = (u16*)alloc((size_t)MPAD * 512 * 2);   // transformed features (bf16, ns-scaled)
    u16* HX   = (u16*)alloc((size_t)MPAD * 512 * 2);   // x_bf16 / h1 / h2 / h3 (in-place rotate)
    u16* W1T  = (u16*)alloc((size_t)512 * 512 * 2);
    u16* W2T  = (u16*)alloc((size_t)512 * 512 * 2);
    u16* W3T  = (u16*)alloc((size_t)256 * 512 * 2);
    u16* WpT  = (u16*)alloc((size_t)128 * 256 * 2);
    u16* projb= (u16*)alloc((size_t)N_SEL * N_DIM * 2);
    u16* eb   = (u16*)alloc((size_t)N_C * N_DIM * 2);
    int* degO   = (int*)alloc(N_NODES * 4);
    int* degI   = (int*)alloc(N_NODES * 4);
    int* cursor = (int*)alloc(N_NODES * 4);
    int* offs   = (int*)alloc((N_NODES + 1) * 4);
    float* ns   = (float*)alloc(N_NODES * 4);
    float* nd   = (float*)alloc(N_NODES * 4);
    int* csr    = (int*)alloc(N_EDGES * 4);
    if ((size_t)(p - (char*)d_ws) > ws_size) return;  // scratch too small — bail

    // graph prep
    hipMemsetAsync(degO, 0, (size_t)((char*)offs - (char*)degO), stream);  // degO,degI,cursor
    degrees_kernel<<<(N_EDGES + 255) / 256, 256, 0, stream>>>(src, dst, degO, degI);
    scan_kernel<<<1, 1024, 0, stream>>>(degI, offs);
    fill_csr_kernel<<<(N_EDGES + 255) / 256, 256, 0, stream>>>(src, dst, cursor, offs, csr);
    norms_kernel<<<(N_NODES + 255) / 256, 256, 0, stream>>>(degO, degI, ns, nd);

    // weight transposes + input conversion
    trans_bf16_kernel<<<(512 * 512) / 256, 256, 0, stream>>>(W1, W1T, 512, 512);
    trans_bf16_kernel<<<(512 * 512) / 256, 256, 0, stream>>>(W2, W2T, 512, 512);
    trans_bf16_kernel<<<(512 * 256) / 256, 256, 0, stream>>>(W3, W3T, 512, 256);
    trans_bf16_kernel<<<(256 * 128) / 256, 256, 0, stream>>>(Wp, WpT, 256, 128);
    convert_x_kernel<<<(MPAD * 512 / 4) / 256, 256, 0, stream>>>(x, HX);
    gather_emb_kernel<<<N_C, N_DIM, 0, stream>>>(emb, cidx, eb);

    // layer 1: T = (x @ W1) * ns ; h1 = relu(nd * agg(T) + b1)
    gemm_bf16_nt<<<dim3(MPAD / 128, 512 / 128), 256, 0, stream>>>(
        HX, W1T, nullptr, T, nullptr, ns, N_NODES, nullptr, 512, 512);
    aggregate_kernel<512><<<MPAD, 256, 0, stream>>>(T, csr, offs, nd, b1, HX);
    // layer 2
    gemm_bf16_nt<<<dim3(MPAD / 128, 512 / 128), 256, 0, stream>>>(
        HX, W2T, nullptr, T, nullptr, ns, N_NODES, nullptr, 512, 512);
    aggregate_kernel<512><<<MPAD, 256, 0, stream>>>(T, csr, offs, nd, b2, HX);
    // layer 3 (transform-first: aggregate at 256 feats)
    gemm_bf16_nt<<<dim3(MPAD / 128, 256 / 128), 256, 0, stream>>>(
        HX, W3T, nullptr, T, nullptr, ns, N_NODES, nullptr, 256, 512);
    aggregate_kernel<256><<<MPAD, 128, 0, stream>>>(T, csr, offs, nd, b3, HX);

    // proj = h3[x_indices] @ Wp + bp   (A-row gather fused into GEMM staging)
    gemm_bf16_nt<<<dim3(N_SEL / 128, 1), 256, 0, stream>>>(
        HX, WpT, xidx, projb, nullptr, nullptr, 0, bp, N_DIM, 256);
    // out = e @ proj^T   (fp32 output)
    gemm_bf16_nt<<<dim3(N_C / 128, N_SEL / 128), 256, 0, stream>>>(
        eb, projb, nullptr, nullptr, out, nullptr, 0, nullptr, N_SEL, N_DIM);
}

// Round 2
// 680.055 us; speedup vs baseline: 1.2071x; 1.2071x over previous
//
#include <hip/hip_runtime.h>

typedef unsigned int u32;
typedef unsigned short u16;

#define N_NODES 50000
#define N_EDGES 400000
#define IN_F 512
#define HID 512
#define OUT_F 256
#define N_CELL 1000
#define N_DIM 128
#define N_SEL 8192
#define N_C 1024
#define MPAD 50048  // 391*128, node count padded to 128-row GEMM tiles

typedef __bf16 bf16x8 __attribute__((ext_vector_type(8)));
typedef float f32x4 __attribute__((ext_vector_type(4)));

__device__ __forceinline__ u16 f2bf(float f) {
    u32 u = __builtin_bit_cast(u32, f);
    u32 r = (u + 0x7fffu + ((u >> 16) & 1u)) >> 16;  // RNE
    return (u16)r;
}
__device__ __forceinline__ float bf2f(u32 bits16) {
    return __builtin_bit_cast(float, bits16 << 16);
}

// async 16B global -> LDS (dest = wave-uniform base + lane*16)
__device__ __forceinline__ void async_copy16(const u16* g, u16* l) {
    __builtin_amdgcn_global_load_lds(
        (const __attribute__((address_space(1))) void*)g,
        (__attribute__((address_space(3))) void*)l, 16, 0, 0);
}

// ---------------- graph prep ----------------

__global__ void degrees_kernel(const int* __restrict__ src, const int* __restrict__ dst,
                               int* __restrict__ degO, int* __restrict__ degI) {
    int e = blockIdx.x * 256 + threadIdx.x;
    if (e < N_EDGES) {
        atomicAdd(&degO[src[e]], 1);
        atomicAdd(&degI[dst[e]], 1);
    }
}

// exclusive prefix sum of degI -> offs[0..N_NODES], single block, chunked
__global__ void scan_kernel(const int* __restrict__ deg, int* __restrict__ offs) {
    __shared__ int sh[1024];
    const int t = threadIdx.x;
    const int chunk = (N_NODES + 1023) >> 10;  // 49
    const int start = t * chunk;
    const int end = min(start + chunk, N_NODES);
    int sum = 0;
    for (int i = start; i < end; ++i) sum += deg[i];
    sh[t] = sum;
    __syncthreads();
    for (int off = 1; off < 1024; off <<= 1) {
        int v = (t >= off) ? sh[t - off] : 0;
        __syncthreads();
        sh[t] += v;
        __syncthreads();
    }
    int run = sh[t] - sum;  // exclusive prefix of this chunk
    for (int i = start; i < end; ++i) { offs[i] = run; run += deg[i]; }
    if (end == N_NODES) offs[N_NODES] = run;  // total = N_EDGES
}

__global__ void fill_csr_kernel(const int* __restrict__ src, const int* __restrict__ dst,
                                int* __restrict__ cursor, const int* __restrict__ offs,
                                int* __restrict__ csr) {
    int e = blockIdx.x * 256 + threadIdx.x;
    if (e < N_EDGES) {
        int d = dst[e];
        int slot = atomicAdd(&cursor[d], 1);
        csr[offs[d] + slot] = src[e];
    }
}

__global__ void norms_kernel(const int* __restrict__ degO, const int* __restrict__ degI,
                             float* __restrict__ ns, float* __restrict__ nd) {
    int i = blockIdx.x * 256 + threadIdx.x;
    if (i < N_NODES) {
        ns[i] = degO[i] > 0 ? rsqrtf((float)degO[i]) : 0.f;
        nd[i] = degI[i] > 0 ? rsqrtf((float)degI[i]) : 0.f;
    }
}

// ---------------- conversions ----------------

// src[K][N] fp32 -> dst[N][K] bf16 (weights, small)
__global__ void trans_bf16_kernel(const float* __restrict__ src, u16* __restrict__ dst,
                                  int K, int N) {
    int i = blockIdx.x * 256 + threadIdx.x;
    if (i >= K * N) return;
    int n = i / K, k = i % K;
    dst[i] = f2bf(src[k * N + n]);
}

// x fp32 [N_NODES][512] -> bf16 [MPAD][512], zero pad rows
__global__ void convert_x_kernel(const float* __restrict__ x, u16* __restrict__ xb) {
    int i = blockIdx.x * 256 + threadIdx.x;  // one per 4 elems; grid exact
    int base = i * 4;
    int m = base >> 9;
    ushort4 o;
    if (m < N_NODES) {
        float4 v = *(const float4*)(x + base);
        o.x = f2bf(v.x); o.y = f2bf(v.y); o.z = f2bf(v.z); o.w = f2bf(v.w);
    } else {
        o = make_ushort4(0, 0, 0, 0);
    }
    *(ushort4*)(xb + base) = o;
}

// eb[c][:] = bf16(emb[c_indices[c]][:])
__global__ void gather_emb_kernel(const float* __restrict__ emb, const int* __restrict__ cidx,
                                  u16* __restrict__ eb) {
    int c = blockIdx.x, f = threadIdx.x;
    eb[c * N_DIM + f] = f2bf(emb[(size_t)cidx[c] * N_DIM + f]);
}

// ---------------- MFMA GEMM (NT: A[M][K] bf16, B[N][K] bf16) ----------------
// C = A @ B^T ; optional A-row gather (aidx), row scale, col bias; bf16 or f32 out.
// 128x128 tile, BK=32, 4 waves each 64x64 via 4x4 of 16x16x32 MFMA.
// Staging via global_load_lds width=16 (m97 ladder step). LDS tile is the
// UNPADDED 128x32 layout required by the wave-uniform-base + lane*16 DMA.
__global__ __launch_bounds__(256, 2) void gemm_bf16_nt(
    const u16* __restrict__ A, const u16* __restrict__ B,
    const int* __restrict__ aidx,
    u16* __restrict__ Cb, float* __restrict__ Cf,
    const float* __restrict__ scale, int nScale,
    const float* __restrict__ bias,
    int N, int K) {
    __shared__ __align__(16) u16 As[128 * 32];
    __shared__ __align__(16) u16 Bs[128 * 32];
    const int t = threadIdx.x;
    const int m0 = blockIdx.x * 128, n0 = blockIdx.y * 128;
    const int l = t & 63, w = t >> 6;
    const int wm = (w >> 1) << 6, wn = (w & 1) << 6;
    const int lr = l & 15, quad = l >> 4;

    // staging map: 8 regions of 16 rows; wave w does regions w and w+4.
    // lane i covers (row = region*16 + i/4, kelem = (i&3)*8 .. +8)
    const int lrow = l >> 2;
    const int kof = (l & 3) << 3;
    const int r0 = w, r1 = w + 4;
    int ar0 = m0 + r0 * 16 + lrow;
    int ar1 = m0 + r1 * 16 + lrow;
    if (aidx) { ar0 = aidx[ar0]; ar1 = aidx[ar1]; }
    const u16* gA0 = A + (size_t)ar0 * K + kof;
    const u16* gA1 = A + (size_t)ar1 * K + kof;
    const u16* gB0 = B + (size_t)(n0 + r0 * 16 + lrow) * K + kof;
    const u16* gB1 = B + (size_t)(n0 + r1 * 16 + lrow) * K + kof;
    u16* lA0 = As + r0 * 512;  // wave-uniform LDS bases
    u16* lA1 = As + r1 * 512;
    u16* lB0 = Bs + r0 * 512;
    u16* lB1 = Bs + r1 * 512;

    f32x4 acc[4][4] = {};

    for (int ks = 0; ks < K; ks += 32) {
        async_copy16(gA0 + ks, lA0);
        async_copy16(gA1 + ks, lA1);
        async_copy16(gB0 + ks, lB0);
        async_copy16(gB1 + ks, lB1);
        __syncthreads();  // drains vmcnt -> LDS tiles ready
        bf16x8 af[4], bg[4];
#pragma unroll
        for (int i = 0; i < 4; ++i)
            af[i] = *(const bf16x8*)&As[(wm + i * 16 + lr) * 32 + quad * 8];
#pragma unroll
        for (int j = 0; j < 4; ++j)
            bg[j] = *(const bf16x8*)&Bs[(wn + j * 16 + lr) * 32 + quad * 8];
#pragma unroll
        for (int i = 0; i < 4; ++i)
#pragma unroll
            for (int j = 0; j < 4; ++j)
                acc[i][j] = __builtin_amdgcn_mfma_f32_16x16x32_bf16(af[i], bg[j], acc[i][j], 0, 0, 0);
        __syncthreads();
    }

    // C/D layout (m89-verified): col = lane&15, row = quad*4 + reg
#pragma unroll
    for (int i = 0; i < 4; ++i) {
        int rbase = m0 + wm + i * 16 + quad * 4;
#pragma unroll
        for (int j = 0; j < 4; ++j) {
            int col = n0 + wn + j * 16 + lr;
            float bv = bias ? bias[col] : 0.f;
#pragma unroll
            for (int r = 0; r < 4; ++r) {
                int rg = rbase + r;
                float sc = scale ? (rg < nScale ? scale[rg] : 0.f) : 1.f;
                float v = acc[i][j][r] * sc + bv;
                if (Cb) Cb[(size_t)rg * N + col] = f2bf(v);
                else    Cf[(size_t)rg * N + col] = v;
            }
        }
    }
}

// ---------------- CSR aggregation: H[n] = relu(nd[n] * sum_{s in N(n)} T[s] + b) ----------------
// One WAVE per node: 64 lanes x (F/64) elems = full row per load instruction.
// Scalar (s_load) edge indices; edge loop unrolled x4 with independent chains.
template <int W32>  // u32 words per lane: 4 (F=512) or 2 (F=256)
struct AggVec;
template <> struct AggVec<4> { using T = uint4; };
template <> struct AggVec<2> { using T = uint2; };

template <int F>
__global__ __launch_bounds__(256) void aggregate_kernel(
    const u16* __restrict__ T, const int* __restrict__ csr,
    const int* __restrict__ offs, const float* __restrict__ nd,
    const float* __restrict__ bias, u16* __restrict__ H) {
    constexpr int W32 = F / 128;  // u32 words per lane
    using VT = typename AggVec<W32>::T;
    const int t = threadIdx.x, w = t >> 6, l = t & 63;
    const int node = blockIdx.x * 4 + w;
    u32* __restrict__ Hrow = (u32*)H + (size_t)node * (F / 2) + l * W32;
    if (node >= N_NODES) {
        VT z = {};
        *(VT*)Hrow = z;
        return;
    }
    const int s0 = __builtin_amdgcn_readfirstlane(offs[node]);
    const int s1 = __builtin_amdgcn_readfirstlane(offs[node + 1]);
    const u32* __restrict__ Tb = (const u32*)T + l * W32;

    float acc[4][2 * W32];
#pragma unroll
    for (int c = 0; c < 4; ++c)
#pragma unroll
        for (int j = 0; j < 2 * W32; ++j) acc[c][j] = 0.f;

    int e = s0;
    for (; e + 4 <= s1; e += 4) {
        int si[4];
#pragma unroll
        for (int c = 0; c < 4; ++c) si[c] = csr[e + c];
        VT v[4];
#pragma unroll
        for (int c = 0; c < 4; ++c)
            v[c] = *(const VT*)(Tb + (size_t)si[c] * (F / 2));
#pragma unroll
        for (int c = 0; c < 4; ++c) {
            const u32* vv = (const u32*)&v[c];
#pragma unroll
            for (int j = 0; j < W32; ++j) {
                acc[c][2 * j] += bf2f(vv[j] & 0xffffu);
                acc[c][2 * j + 1] += bf2f(vv[j] >> 16);
            }
        }
    }
    for (; e < s1; ++e) {
        int s = csr[e];
        VT v = *(const VT*)(Tb + (size_t)s * (F / 2));
        const u32* vv = (const u32*)&v;
#pragma unroll
        for (int j = 0; j < W32; ++j) {
            acc[0][2 * j] += bf2f(vv[j] & 0xffffu);
            acc[0][2 * j + 1] += bf2f(vv[j] >> 16);
        }
    }

    const float ndv = nd[node];
    u32 ow[W32];
#pragma unroll
    for (int j = 0; j < W32; ++j) {
        float a0 = acc[0][2 * j] + acc[1][2 * j] + acc[2][2 * j] + acc[3][2 * j];
        float a1 = acc[0][2 * j + 1] + acc[1][2 * j + 1] + acc[2][2 * j + 1] + acc[3][2 * j + 1];
        float r0 = fmaxf(fmaf(a0, ndv, bias[l * 2 * W32 + 2 * j]), 0.f);
        float r1 = fmaxf(fmaf(a1, ndv, bias[l * 2 * W32 + 2 * j + 1]), 0.f);
        ow[j] = (u32)f2bf(r0) | ((u32)f2bf(r1) << 16);
    }
    VT o;
    u32* op = (u32*)&o;
#pragma unroll
    for (int j = 0; j < W32; ++j) op[j] = ow[j];
    *(VT*)Hrow = o;
}

// ---------------- launch ----------------

extern "C" void kernel_launch(void* const* d_in, const int* in_sizes, int n_in,
                              void* d_out, int out_size, void* d_ws, size_t ws_size,
                              hipStream_t stream) {
    const float* x   = (const float*)d_in[0];
    const int*   src = (const int*)d_in[1];
    const int*   dst = (const int*)d_in[2];
    const int*   xidx= (const int*)d_in[3];
    const int*   cidx= (const int*)d_in[4];
    const float* W1  = (const float*)d_in[5];
    const float* b1  = (const float*)d_in[6];
    const float* W2  = (const float*)d_in[7];
    const float* b2  = (const float*)d_in[8];
    const float* W3  = (const float*)d_in[9];
    const float* b3  = (const float*)d_in[10];
    const float* Wp  = (const float*)d_in[11];
    const float* bp  = (const float*)d_in[12];
    const float* emb = (const float*)d_in[13];
    float* out = (float*)d_out;

    char* p = (char*)d_ws;
    auto alloc = [&](size_t bytes) {
        char* r = p;
        p += (bytes + 255) & ~(size_t)255;
        return r;
    };
    u16* T    = (u16*)alloc((size_t)MPAD * 512 * 2);   // transformed features (bf16, ns-scaled)
    u16* HX   = (u16*)alloc((size_t)MPAD * 512 * 2);   // x_bf16 / h1 / h2 / h3 (in-place rotate)
    u16* W1T  = (u16*)alloc((size_t)512 * 512 * 2);
    u16* W2T  = (u16*)alloc((size_t)512 * 512 * 2);
    u16* W3T  = (u16*)alloc((size_t)256 * 512 * 2);
    u16* WpT  = (u16*)alloc((size_t)128 * 256 * 2);
    u16* projb= (u16*)alloc((size_t)N_SEL * N_DIM * 2);
    u16* eb   = (u16*)alloc((size_t)N_C * N_DIM * 2);
    int* degO   = (int*)alloc(N_NODES * 4);
    int* degI   = (int*)alloc(N_NODES * 4);
    int* cursor = (int*)alloc(N_NODES * 4);
    int* offs   = (int*)alloc((N_NODES + 1) * 4);
    float* ns   = (float*)alloc(N_NODES * 4);
    float* nd   = (float*)alloc(N_NODES * 4);
    int* csr    = (int*)alloc(N_EDGES * 4);
    if ((size_t)(p - (char*)d_ws) > ws_size) return;  // scratch too small — bail

    // graph prep
    hipMemsetAsync(degO, 0, (size_t)((char*)offs - (char*)degO), stream);  // degO,degI,cursor
    degrees_kernel<<<(N_EDGES + 255) / 256, 256, 0, stream>>>(src, dst, degO, degI);
    scan_kernel<<<1, 1024, 0, stream>>>(degI, offs);
    fill_csr_kernel<<<(N_EDGES + 255) / 256, 256, 0, stream>>>(src, dst, cursor, offs, csr);
    norms_kernel<<<(N_NODES + 255) / 256, 256, 0, stream>>>(degO, degI, ns, nd);

    // weight transposes + input conversion
    trans_bf16_kernel<<<(512 * 512) / 256, 256, 0, stream>>>(W1, W1T, 512, 512);
    trans_bf16_kernel<<<(512 * 512) / 256, 256, 0, stream>>>(W2, W2T, 512, 512);
    trans_bf16_kernel<<<(512 * 256) / 256, 256, 0, stream>>>(W3, W3T, 512, 256);
    trans_bf16_kernel<<<(256 * 128) / 256, 256, 0, stream>>>(Wp, WpT, 256, 128);
    convert_x_kernel<<<(MPAD * 512 / 4) / 256, 256, 0, stream>>>(x, HX);
    gather_emb_kernel<<<N_C, N_DIM, 0, stream>>>(emb, cidx, eb);

    // layer 1: T = (x @ W1) * ns ; h1 = relu(nd * agg(T) + b1)
    gemm_bf16_nt<<<dim3(MPAD / 128, 512 / 128), 256, 0, stream>>>(
        HX, W1T, nullptr, T, nullptr, ns, N_NODES, nullptr, 512, 512);
    aggregate_kernel<512><<<MPAD / 4, 256, 0, stream>>>(T, csr, offs, nd, b1, HX);
    // layer 2
    gemm_bf16_nt<<<dim3(MPAD / 128, 512 / 128), 256, 0, stream>>>(
        HX, W2T, nullptr, T, nullptr, ns, N_NODES, nullptr, 512, 512);
    aggregate_kernel<512><<<MPAD / 4, 256, 0, stream>>>(T, csr, offs, nd, b2, HX);
    // layer 3 (transform-first: aggregate at 256 feats)
    gemm_bf16_nt<<<dim3(MPAD / 128, 256 / 128), 256, 0, stream>>>(
        HX, W3T, nullptr, T, nullptr, ns, N_NODES, nullptr, 256, 512);
    aggregate_kernel<256><<<MPAD / 4, 256, 0, stream>>>(T, csr, offs, nd, b3, HX);

    // proj = h3[x_indices] @ Wp + bp   (A-row gather fused into GEMM staging)
    gemm_bf16_nt<<<dim3(N_SEL / 128, 1), 256, 0, stream>>>(
        HX, WpT, xidx, projb, nullptr, nullptr, 0, bp, N_DIM, 256);
    // out = e @ proj^T   (fp32 output)
    gemm_bf16_nt<<<dim3(N_C / 128, N_SEL / 128), 256, 0, stream>>>(
        eb, projb, nullptr, nullptr, out, nullptr, 0, nullptr, N_SEL, N_DIM);
}

// Round 3
// 612.657 us; speedup vs baseline: 1.3399x; 1.1100x over previous
//
#include <hip/hip_runtime.h>

typedef unsigned int u32;
typedef unsigned short u16;

#define N_NODES 50000
#define N_EDGES 400000
#define IN_F 512
#define HID 512
#define OUT_F 256
#define N_CELL 1000
#define N_DIM 128
#define N_SEL 8192
#define N_C 1024
#define MPAD 50048  // 391*128, node count padded to 128-row GEMM tiles

#define SCAN_B 256
#define SCAN_NB ((N_NODES + SCAN_B - 1) / SCAN_B)  // 196

typedef __bf16 bf16x8 __attribute__((ext_vector_type(8)));
typedef float f32x4 __attribute__((ext_vector_type(4)));

__device__ __forceinline__ u16 f2bf(float f) {
    u32 u = __builtin_bit_cast(u32, f);
    u32 r = (u + 0x7fffu + ((u >> 16) & 1u)) >> 16;  // RNE
    return (u16)r;
}
__device__ __forceinline__ float bf2f(u32 bits16) {
    return __builtin_bit_cast(float, bits16 << 16);
}

// async 16B global -> LDS (dest = wave-uniform base + lane*16)
__device__ __forceinline__ void async_copy16(const u16* g, u16* l) {
    __builtin_amdgcn_global_load_lds(
        (const __attribute__((address_space(1))) void*)g,
        (__attribute__((address_space(3))) void*)l, 16, 0, 0);
}

// ---------------- graph prep ----------------

__global__ void degrees_kernel(const int* __restrict__ src, const int* __restrict__ dst,
                               int* __restrict__ degO, int* __restrict__ degI) {
    int e = blockIdx.x * 256 + threadIdx.x;
    if (e < N_EDGES) {
        atomicAdd(&degO[src[e]], 1);
        atomicAdd(&degI[dst[e]], 1);
    }
}

// --- 3-phase parallel exclusive scan of degI -> offs[0..N_NODES] ---
__global__ void scan_blocksum_kernel(const int* __restrict__ deg, int* __restrict__ bsum) {
    __shared__ int sh[SCAN_B];
    int i = blockIdx.x * SCAN_B + threadIdx.x;
    int v = (i < N_NODES) ? deg[i] : 0;
    sh[threadIdx.x] = v;
    __syncthreads();
    for (int off = SCAN_B / 2; off > 0; off >>= 1) {
        if (threadIdx.x < off) sh[threadIdx.x] += sh[threadIdx.x + off];
        __syncthreads();
    }
    if (threadIdx.x == 0) bsum[blockIdx.x] = sh[0];
}

__global__ void scan_bsum_kernel(const int* __restrict__ bsum, int* __restrict__ boff) {
    __shared__ int sh[SCAN_B];
    const int t = threadIdx.x;
    int v = (t < SCAN_NB) ? bsum[t] : 0;
    sh[t] = v;
    __syncthreads();
    for (int off = 1; off < SCAN_B; off <<= 1) {
        int u = (t >= off) ? sh[t - off] : 0;
        __syncthreads();
        sh[t] += u;
        __syncthreads();
    }
    if (t < SCAN_NB) boff[t] = sh[t] - v;  // exclusive
}

__global__ void scan_final_kernel(const int* __restrict__ deg, const int* __restrict__ boff,
                                  int* __restrict__ offs) {
    __shared__ int sh[SCAN_B];
    const int t = threadIdx.x;
    int i = blockIdx.x * SCAN_B + t;
    int v = (i < N_NODES) ? deg[i] : 0;
    sh[t] = v;
    __syncthreads();
    for (int off = 1; off < SCAN_B; off <<= 1) {
        int u = (t >= off) ? sh[t - off] : 0;
        __syncthreads();
        sh[t] += u;
        __syncthreads();
    }
    if (i < N_NODES) offs[i] = boff[blockIdx.x] + sh[t] - v;
    if (i == 0) offs[N_NODES] = N_EDGES;  // total degree = edge count
}

__global__ void fill_csr_kernel(const int* __restrict__ src, const int* __restrict__ dst,
                                int* __restrict__ cursor, const int* __restrict__ offs,
                                int* __restrict__ csr) {
    int e = blockIdx.x * 256 + threadIdx.x;
    if (e < N_EDGES) {
        int d = dst[e];
        int slot = atomicAdd(&cursor[d], 1);
        csr[offs[d] + slot] = src[e];
    }
}

__global__ void norms_kernel(const int* __restrict__ degO, const int* __restrict__ degI,
                             float* __restrict__ ns, float* __restrict__ nd) {
    int i = blockIdx.x * 256 + threadIdx.x;
    if (i < N_NODES) {
        ns[i] = degO[i] > 0 ? rsqrtf((float)degO[i]) : 0.f;
        nd[i] = degI[i] > 0 ? rsqrtf((float)degI[i]) : 0.f;
    }
}

// ---------------- conversions ----------------

// src[K][N] fp32 -> dst[N][K] bf16 (weights, small)
__global__ void trans_bf16_kernel(const float* __restrict__ src, u16* __restrict__ dst,
                                  int K, int N) {
    int i = blockIdx.x * 256 + threadIdx.x;
    if (i >= K * N) return;
    int n = i / K, k = i % K;
    dst[i] = f2bf(src[k * N + n]);
}

// x fp32 [N_NODES][512] -> bf16 [MPAD][512], zero pad rows
__global__ void convert_x_kernel(const float* __restrict__ x, u16* __restrict__ xb) {
    int i = blockIdx.x * 256 + threadIdx.x;  // one per 4 elems; grid exact
    int base = i * 4;
    int m = base >> 9;
    ushort4 o;
    if (m < N_NODES) {
        float4 v = *(const float4*)(x + base);
        o.x = f2bf(v.x); o.y = f2bf(v.y); o.z = f2bf(v.z); o.w = f2bf(v.w);
    } else {
        o = make_ushort4(0, 0, 0, 0);
    }
    *(ushort4*)(xb + base) = o;
}

// eb[c][:] = bf16(emb[c_indices[c]][:])
__global__ void gather_emb_kernel(const float* __restrict__ emb, const int* __restrict__ cidx,
                                  u16* __restrict__ eb) {
    int c = blockIdx.x, f = threadIdx.x;
    eb[c * N_DIM + f] = f2bf(emb[(size_t)cidx[c] * N_DIM + f]);
}

// ---------------- MFMA GEMM (NT: A[M][K] bf16, B[N][K] bf16) ----------------
// C = A @ B^T ; optional A-row gather (aidx), row scale, col bias; bf16 or f32 out.
// 128x128 tile, BK=32, 4 waves each 64x64 via 4x4 of 16x16x32 MFMA.
// Staging via global_load_lds width=16 (m97 ladder step). LDS tile is the
// UNPADDED 128x32 layout required by the wave-uniform-base + lane*16 DMA.
__global__ __launch_bounds__(256, 2) void gemm_bf16_nt(
    const u16* __restrict__ A, const u16* __restrict__ B,
    const int* __restrict__ aidx,
    u16* __restrict__ Cb, float* __restrict__ Cf,
    const float* __restrict__ scale, int nScale,
    const float* __restrict__ bias,
    int N, int K) {
    __shared__ __align__(16) u16 As[128 * 32];
    __shared__ __align__(16) u16 Bs[128 * 32];
    const int t = threadIdx.x;
    const int m0 = blockIdx.x * 128, n0 = blockIdx.y * 128;
    const int l = t & 63, w = t >> 6;
    const int wm = (w >> 1) << 6, wn = (w & 1) << 6;
    const int lr = l & 15, quad = l >> 4;

    // staging map: 8 regions of 16 rows; wave w does regions w and w+4.
    // lane i covers (row = region*16 + i/4, kelem = (i&3)*8 .. +8)
    const int lrow = l >> 2;
    const int kof = (l & 3) << 3;
    const int r0 = w, r1 = w + 4;
    int ar0 = m0 + r0 * 16 + lrow;
    int ar1 = m0 + r1 * 16 + lrow;
    if (aidx) { ar0 = aidx[ar0]; ar1 = aidx[ar1]; }
    const u16* gA0 = A + (size_t)ar0 * K + kof;
    const u16* gA1 = A + (size_t)ar1 * K + kof;
    const u16* gB0 = B + (size_t)(n0 + r0 * 16 + lrow) * K + kof;
    const u16* gB1 = B + (size_t)(n0 + r1 * 16 + lrow) * K + kof;
    u16* lA0 = As + r0 * 512;  // wave-uniform LDS bases
    u16* lA1 = As + r1 * 512;
    u16* lB0 = Bs + r0 * 512;
    u16* lB1 = Bs + r1 * 512;

    f32x4 acc[4][4] = {};

    for (int ks = 0; ks < K; ks += 32) {
        async_copy16(gA0 + ks, lA0);
        async_copy16(gA1 + ks, lA1);
        async_copy16(gB0 + ks, lB0);
        async_copy16(gB1 + ks, lB1);
        __syncthreads();  // drains vmcnt -> LDS tiles ready
        bf16x8 af[4], bg[4];
#pragma unroll
        for (int i = 0; i < 4; ++i)
            af[i] = *(const bf16x8*)&As[(wm + i * 16 + lr) * 32 + quad * 8];
#pragma unroll
        for (int j = 0; j < 4; ++j)
            bg[j] = *(const bf16x8*)&Bs[(wn + j * 16 + lr) * 32 + quad * 8];
#pragma unroll
        for (int i = 0; i < 4; ++i)
#pragma unroll
            for (int j = 0; j < 4; ++j)
                acc[i][j] = __builtin_amdgcn_mfma_f32_16x16x32_bf16(af[i], bg[j], acc[i][j], 0, 0, 0);
        __syncthreads();
    }

    // C/D layout (m89-verified): col = lane&15, row = quad*4 + reg
#pragma unroll
    for (int i = 0; i < 4; ++i) {
        int rbase = m0 + wm + i * 16 + quad * 4;
#pragma unroll
        for (int j = 0; j < 4; ++j) {
            int col = n0 + wn + j * 16 + lr;
            float bv = bias ? bias[col] : 0.f;
#pragma unroll
            for (int r = 0; r < 4; ++r) {
                int rg = rbase + r;
                float sc = scale ? (rg < nScale ? scale[rg] : 0.f) : 1.f;
                float v = acc[i][j][r] * sc + bv;
                if (Cb) Cb[(size_t)rg * N + col] = f2bf(v);
                else    Cf[(size_t)rg * N + col] = v;
            }
        }
    }
}

// ---------------- CSR aggregation: H[n] = relu(nd[n] * sum_{s in N(n)} T[s] + b) ----------------
// One WAVE per node: 64 lanes x (F/64) elems = full row per load instruction.
// Scalar (s_load) edge indices; edge loop unrolled x4 with independent chains.
template <int W32>  // u32 words per lane: 4 (F=512) or 2 (F=256)
struct AggVec;
template <> struct AggVec<4> { using T = uint4; };
template <> struct AggVec<2> { using T = uint2; };

template <int F>
__global__ __launch_bounds__(256) void aggregate_kernel(
    const u16* __restrict__ T, const int* __restrict__ csr,
    const int* __restrict__ offs, const float* __restrict__ nd,
    const float* __restrict__ bias, u16* __restrict__ H) {
    constexpr int W32 = F / 128;  // u32 words per lane
    using VT = typename AggVec<W32>::T;
    const int t = threadIdx.x, w = t >> 6, l = t & 63;
    const int node = blockIdx.x * 4 + w;
    u32* __restrict__ Hrow = (u32*)H + (size_t)node * (F / 2) + l * W32;
    if (node >= N_NODES) {
        VT z = {};
        *(VT*)Hrow = z;
        return;
    }
    const int s0 = __builtin_amdgcn_readfirstlane(offs[node]);
    const int s1 = __builtin_amdgcn_readfirstlane(offs[node + 1]);
    const u32* __restrict__ Tb = (const u32*)T + l * W32;

    float acc[4][2 * W32];
#pragma unroll
    for (int c = 0; c < 4; ++c)
#pragma unroll
        for (int j = 0; j < 2 * W32; ++j) acc[c][j] = 0.f;

    int e = s0;
    for (; e + 4 <= s1; e += 4) {
        int si[4];
#pragma unroll
        for (int c = 0; c < 4; ++c) si[c] = csr[e + c];
        VT v[4];
#pragma unroll
        for (int c = 0; c < 4; ++c)
            v[c] = *(const VT*)(Tb + (size_t)si[c] * (F / 2));
#pragma unroll
        for (int c = 0; c < 4; ++c) {
            const u32* vv = (const u32*)&v[c];
#pragma unroll
            for (int j = 0; j < W32; ++j) {
                acc[c][2 * j] += bf2f(vv[j] & 0xffffu);
                acc[c][2 * j + 1] += bf2f(vv[j] >> 16);
            }
        }
    }
    for (; e < s1; ++e) {
        int s = csr[e];
        VT v = *(const VT*)(Tb + (size_t)s * (F / 2));
        const u32* vv = (const u32*)&v;
#pragma unroll
        for (int j = 0; j < W32; ++j) {
            acc[0][2 * j] += bf2f(vv[j] & 0xffffu);
            acc[0][2 * j + 1] += bf2f(vv[j] >> 16);
        }
    }

    const float ndv = nd[node];
    u32 ow[W32];
#pragma unroll
    for (int j = 0; j < W32; ++j) {
        float a0 = acc[0][2 * j] + acc[1][2 * j] + acc[2][2 * j] + acc[3][2 * j];
        float a1 = acc[0][2 * j + 1] + acc[1][2 * j + 1] + acc[2][2 * j + 1] + acc[3][2 * j + 1];
        float r0 = fmaxf(fmaf(a0, ndv, bias[l * 2 * W32 + 2 * j]), 0.f);
        float r1 = fmaxf(fmaf(a1, ndv, bias[l * 2 * W32 + 2 * j + 1]), 0.f);
        ow[j] = (u32)f2bf(r0) | ((u32)f2bf(r1) << 16);
    }
    VT o;
    u32* op = (u32*)&o;
#pragma unroll
    for (int j = 0; j < W32; ++j) op[j] = ow[j];
    *(VT*)Hrow = o;
}

// ---------------- launch ----------------

extern "C" void kernel_launch(void* const* d_in, const int* in_sizes, int n_in,
                              void* d_out, int out_size, void* d_ws, size_t ws_size,
                              hipStream_t stream) {
    const float* x   = (const float*)d_in[0];
    const int*   src = (const int*)d_in[1];
    const int*   dst = (const int*)d_in[2];
    const int*   xidx= (const int*)d_in[3];
    const int*   cidx= (const int*)d_in[4];
    const float* W1  = (const float*)d_in[5];
    const float* b1  = (const float*)d_in[6];
    const float* W2  = (const float*)d_in[7];
    const float* b2  = (const float*)d_in[8];
    const float* W3  = (const float*)d_in[9];
    const float* b3  = (const float*)d_in[10];
    const float* Wp  = (const float*)d_in[11];
    const float* bp  = (const float*)d_in[12];
    const float* emb = (const float*)d_in[13];
    float* out = (float*)d_out;

    char* p = (char*)d_ws;
    auto alloc = [&](size_t bytes) {
        char* r = p;
        p += (bytes + 255) & ~(size_t)255;
        return r;
    };
    u16* T    = (u16*)alloc((size_t)MPAD * 512 * 2);   // transformed features (bf16, ns-scaled)
    u16* HX   = (u16*)alloc((size_t)MPAD * 512 * 2);   // x_bf16 / h1 / h2 / h3 (in-place rotate)
    u16* W1T  = (u16*)alloc((size_t)512 * 512 * 2);
    u16* W2T  = (u16*)alloc((size_t)512 * 512 * 2);
    u16* W3T  = (u16*)alloc((size_t)256 * 512 * 2);
    u16* WpT  = (u16*)alloc((size_t)128 * 256 * 2);
    u16* projb= (u16*)alloc((size_t)N_SEL * N_DIM * 2);
    u16* eb   = (u16*)alloc((size_t)N_C * N_DIM * 2);
    int* degO   = (int*)alloc(N_NODES * 4);
    int* degI   = (int*)alloc(N_NODES * 4);
    int* cursor = (int*)alloc(N_NODES * 4);
    int* offs   = (int*)alloc((N_NODES + 1) * 4);
    float* ns   = (float*)alloc(N_NODES * 4);
    float* nd   = (float*)alloc(N_NODES * 4);
    int* csr    = (int*)alloc(N_EDGES * 4);
    int* bsum   = (int*)alloc(SCAN_NB * 4);
    int* boff   = (int*)alloc(SCAN_NB * 4);
    if ((size_t)(p - (char*)d_ws) > ws_size) return;  // scratch too small — bail

    // graph prep
    hipMemsetAsync(degO, 0, (size_t)((char*)offs - (char*)degO), stream);  // degO,degI,cursor
    degrees_kernel<<<(N_EDGES + 255) / 256, 256, 0, stream>>>(src, dst, degO, degI);
    scan_blocksum_kernel<<<SCAN_NB, SCAN_B, 0, stream>>>(degI, bsum);
    scan_bsum_kernel<<<1, SCAN_B, 0, stream>>>(bsum, boff);
    scan_final_kernel<<<SCAN_NB, SCAN_B, 0, stream>>>(degI, boff, offs);
    fill_csr_kernel<<<(N_EDGES + 255) / 256, 256, 0, stream>>>(src, dst, cursor, offs, csr);
    norms_kernel<<<(N_NODES + 255) / 256, 256, 0, stream>>>(degO, degI, ns, nd);

    // weight transposes + input conversion
    trans_bf16_kernel<<<(512 * 512) / 256, 256, 0, stream>>>(W1, W1T, 512, 512);
    trans_bf16_kernel<<<(512 * 512) / 256, 256, 0, stream>>>(W2, W2T, 512, 512);
    trans_bf16_kernel<<<(512 * 256) / 256, 256, 0, stream>>>(W3, W3T, 512, 256);
    trans_bf16_kernel<<<(256 * 128) / 256, 256, 0, stream>>>(Wp, WpT, 256, 128);
    convert_x_kernel<<<(MPAD * 512 / 4) / 256, 256, 0, stream>>>(x, HX);
    gather_emb_kernel<<<N_C, N_DIM, 0, stream>>>(emb, cidx, eb);

    // layer 1: T = (x @ W1) * ns ; h1 = relu(nd * agg(T) + b1)
    gemm_bf16_nt<<<dim3(MPAD / 128, 512 / 128), 256, 0, stream>>>(
        HX, W1T, nullptr, T, nullptr, ns, N_NODES, nullptr, 512, 512);
    aggregate_kernel<512><<<MPAD / 4, 256, 0, stream>>>(T, csr, offs, nd, b1, HX);
    // layer 2
    gemm_bf16_nt<<<dim3(MPAD / 128, 512 / 128), 256, 0, stream>>>(
        HX, W2T, nullptr, T, nullptr, ns, N_NODES, nullptr, 512, 512);
    aggregate_kernel<512><<<MPAD / 4, 256, 0, stream>>>(T, csr, offs, nd, b2, HX);
    // layer 3 (transform-first: aggregate at 256 feats)
    gemm_bf16_nt<<<dim3(MPAD / 128, 256 / 128), 256, 0, stream>>>(
        HX, W3T, nullptr, T, nullptr, ns, N_NODES, nullptr, 256, 512);
    aggregate_kernel<256><<<MPAD / 4, 256, 0, stream>>>(T, csr, offs, nd, b3, HX);

    // proj = h3[x_indices] @ Wp + bp   (A-row gather fused into GEMM staging)
    gemm_bf16_nt<<<dim3(N_SEL / 128, 1), 256, 0, stream>>>(
        HX, WpT, xidx, projb, nullptr, nullptr, 0, bp, N_DIM, 256);
    // out = e @ proj^T   (fp32 output)
    gemm_bf16_nt<<<dim3(N_C / 128, N_SEL / 128), 256, 0, stream>>>(
        eb, projb, nullptr, nullptr, out, nullptr, 0, nullptr, N_SEL, N_DIM);
}

// Round 4
// 612.560 us; speedup vs baseline: 1.3401x; 1.0002x over previous
//
#include <hip/hip_runtime.h>

typedef unsigned int u32;
typedef unsigned short u16;

#define N_NODES 50000
#define N_EDGES 400000
#define IN_F 512
#define HID 512
#define OUT_F 256
#define N_CELL 1000
#define N_DIM 128
#define N_SEL 8192
#define N_C 1024
#define MPAD 50176  // 196*256, node count padded to 256-row GEMM tiles

#define SCAN_B 256
#define SCAN_NB ((N_NODES + SCAN_B - 1) / SCAN_B)  // 196

typedef __bf16 bf16x8 __attribute__((ext_vector_type(8)));
typedef float f32x4 __attribute__((ext_vector_type(4)));

__device__ __forceinline__ u16 f2bf(float f) {
    u32 u = __builtin_bit_cast(u32, f);
    u32 r = (u + 0x7fffu + ((u >> 16) & 1u)) >> 16;  // RNE
    return (u16)r;
}
__device__ __forceinline__ float bf2f(u32 bits16) {
    return __builtin_bit_cast(float, bits16 << 16);
}

// async 16B global -> LDS (dest = wave-uniform base + lane*16)
__device__ __forceinline__ void async_copy16(const u16* g, u16* l) {
    __builtin_amdgcn_global_load_lds(
        (const __attribute__((address_space(1))) void*)g,
        (__attribute__((address_space(3))) void*)l, 16, 0, 0);
}

// ---------------- graph prep ----------------

__global__ void degrees_kernel(const int* __restrict__ src, const int* __restrict__ dst,
                               int* __restrict__ degO, int* __restrict__ degI) {
    int e = blockIdx.x * 256 + threadIdx.x;
    if (e < N_EDGES) {
        atomicAdd(&degO[src[e]], 1);
        atomicAdd(&degI[dst[e]], 1);
    }
}

// --- 3-phase parallel exclusive scan of degI -> offs[0..N_NODES] ---
__global__ void scan_blocksum_kernel(const int* __restrict__ deg, int* __restrict__ bsum) {
    __shared__ int sh[SCAN_B];
    int i = blockIdx.x * SCAN_B + threadIdx.x;
    int v = (i < N_NODES) ? deg[i] : 0;
    sh[threadIdx.x] = v;
    __syncthreads();
    for (int off = SCAN_B / 2; off > 0; off >>= 1) {
        if (threadIdx.x < off) sh[threadIdx.x] += sh[threadIdx.x + off];
        __syncthreads();
    }
    if (threadIdx.x == 0) bsum[blockIdx.x] = sh[0];
}

__global__ void scan_bsum_kernel(const int* __restrict__ bsum, int* __restrict__ boff) {
    __shared__ int sh[SCAN_B];
    const int t = threadIdx.x;
    int v = (t < SCAN_NB) ? bsum[t] : 0;
    sh[t] = v;
    __syncthreads();
    for (int off = 1; off < SCAN_B; off <<= 1) {
        int u = (t >= off) ? sh[t - off] : 0;
        __syncthreads();
        sh[t] += u;
        __syncthreads();
    }
    if (t < SCAN_NB) boff[t] = sh[t] - v;  // exclusive
}

__global__ void scan_final_kernel(const int* __restrict__ deg, const int* __restrict__ boff,
                                  int* __restrict__ offs) {
    __shared__ int sh[SCAN_B];
    const int t = threadIdx.x;
    int i = blockIdx.x * SCAN_B + t;
    int v = (i < N_NODES) ? deg[i] : 0;
    sh[t] = v;
    __syncthreads();
    for (int off = 1; off < SCAN_B; off <<= 1) {
        int u = (t >= off) ? sh[t - off] : 0;
        __syncthreads();
        sh[t] += u;
        __syncthreads();
    }
    if (i < N_NODES) offs[i] = boff[blockIdx.x] + sh[t] - v;
    if (i == 0) offs[N_NODES] = N_EDGES;  // total degree = edge count
}

__global__ void fill_csr_kernel(const int* __restrict__ src, const int* __restrict__ dst,
                                int* __restrict__ cursor, const int* __restrict__ offs,
                                int* __restrict__ csr) {
    int e = blockIdx.x * 256 + threadIdx.x;
    if (e < N_EDGES) {
        int d = dst[e];
        int slot = atomicAdd(&cursor[d], 1);
        csr[offs[d] + slot] = src[e];
    }
}

__global__ void norms_kernel(const int* __restrict__ degO, const int* __restrict__ degI,
                             float* __restrict__ ns, float* __restrict__ nd) {
    int i = blockIdx.x * 256 + threadIdx.x;
    if (i < N_NODES) {
        ns[i] = degO[i] > 0 ? rsqrtf((float)degO[i]) : 0.f;
        nd[i] = degI[i] > 0 ? rsqrtf((float)degI[i]) : 0.f;
    }
}

// ---------------- conversions ----------------

// src[K][N] fp32 -> dst[N][K] bf16 (weights, small)
__global__ void trans_bf16_kernel(const float* __restrict__ src, u16* __restrict__ dst,
                                  int K, int N) {
    int i = blockIdx.x * 256 + threadIdx.x;
    if (i >= K * N) return;
    int n = i / K, k = i % K;
    dst[i] = f2bf(src[k * N + n]);
}

// x fp32 [N_NODES][512] -> bf16 [MPAD][512], zero pad rows
__global__ void convert_x_kernel(const float* __restrict__ x, u16* __restrict__ xb) {
    int i = blockIdx.x * 256 + threadIdx.x;  // one per 4 elems; grid exact
    int base = i * 4;
    int m = base >> 9;
    ushort4 o;
    if (m < N_NODES) {
        float4 v = *(const float4*)(x + base);
        o.x = f2bf(v.x); o.y = f2bf(v.y); o.z = f2bf(v.z); o.w = f2bf(v.w);
    } else {
        o = make_ushort4(0, 0, 0, 0);
    }
    *(ushort4*)(xb + base) = o;
}

// eb[c][:] = bf16(emb[c_indices[c]][:])
__global__ void gather_emb_kernel(const float* __restrict__ emb, const int* __restrict__ cidx,
                                  u16* __restrict__ eb) {
    int c = blockIdx.x, f = threadIdx.x;
    eb[c * N_DIM + f] = f2bf(emb[(size_t)cidx[c] * N_DIM + f]);
}

// ---------------- MFMA GEMM (NT: A[M][K] bf16, B[N][K] bf16) ----------------
// C = A @ B^T ; optional A-row gather (aidx), row scale, col bias; bf16 or f32 out.
// 256x128 block tile, 512 threads = 8 waves, wave tile 64x64 (4x4 of 16x16x32).
// Regs ~120/wave -> 4 waves/SIMD -> 2 blocks/CU = 16 waves/CU resident; each
// barrier fences 2x the pipe work of the old 128x128 tile (drain amortization).
// Staging via global_load_lds width=16; UNPADDED 256x32 / 128x32 LDS layout
// (wave-uniform base + lane*16 DMA constraint).
__global__ __launch_bounds__(512, 4) void gemm_bf16_nt(
    const u16* __restrict__ A, const u16* __restrict__ B,
    const int* __restrict__ aidx,
    u16* __restrict__ Cb, float* __restrict__ Cf,
    const float* __restrict__ scale, int nScale,
    const float* __restrict__ bias,
    int N, int K) {
    __shared__ __align__(16) u16 As[256 * 32];  // 16 KB
    __shared__ __align__(16) u16 Bs[128 * 32];  // 8 KB
    const int t = threadIdx.x;
    const int m0 = blockIdx.x * 256, n0 = blockIdx.y * 128;
    const int l = t & 63, w = t >> 6;           // 8 waves
    const int wm = (w >> 1) << 6;               // 0,64,128,192
    const int wn = (w & 1) << 6;                // 0,64
    const int lr = l & 15, quad = l >> 4;

    // staging regions: 16 rows x 32 k-elems = 1 KB per wave-DMA.
    // A: 16 regions -> wave w does regions w and w+8; B: 8 regions -> wave w.
    const int lrow = l >> 2;            // row within region
    const int kof = (l & 3) << 3;       // k-elem offset within row
    int ar0 = m0 + w * 16 + lrow;
    int ar1 = m0 + (w + 8) * 16 + lrow;
    if (aidx) { ar0 = aidx[ar0]; ar1 = aidx[ar1]; }
    const u16* gA0 = A + (size_t)ar0 * K + kof;
    const u16* gA1 = A + (size_t)ar1 * K + kof;
    const u16* gB0 = B + (size_t)(n0 + w * 16 + lrow) * K + kof;
    u16* lA0 = As + w * 512;        // wave-uniform LDS bases (region = 512 u16)
    u16* lA1 = As + (w + 8) * 512;
    u16* lB0 = Bs + w * 512;

    f32x4 acc[4][4] = {};

    for (int ks = 0; ks < K; ks += 32) {
        async_copy16(gA0 + ks, lA0);
        async_copy16(gA1 + ks, lA1);
        async_copy16(gB0 + ks, lB0);
        __syncthreads();  // drains vmcnt -> LDS tiles ready
        bf16x8 af[4], bg[4];
#pragma unroll
        for (int i = 0; i < 4; ++i)
            af[i] = *(const bf16x8*)&As[(wm + i * 16 + lr) * 32 + quad * 8];
#pragma unroll
        for (int j = 0; j < 4; ++j)
            bg[j] = *(const bf16x8*)&Bs[(wn + j * 16 + lr) * 32 + quad * 8];
#pragma unroll
        for (int i = 0; i < 4; ++i)
#pragma unroll
            for (int j = 0; j < 4; ++j)
                acc[i][j] = __builtin_amdgcn_mfma_f32_16x16x32_bf16(af[i], bg[j], acc[i][j], 0, 0, 0);
        __syncthreads();
    }

    // C/D layout (m89-verified): col = lane&15, row = quad*4 + reg
#pragma unroll
    for (int i = 0; i < 4; ++i) {
        int rbase = m0 + wm + i * 16 + quad * 4;
#pragma unroll
        for (int j = 0; j < 4; ++j) {
            int col = n0 + wn + j * 16 + lr;
            float bv = bias ? bias[col] : 0.f;
#pragma unroll
            for (int r = 0; r < 4; ++r) {
                int rg = rbase + r;
                float sc = scale ? (rg < nScale ? scale[rg] : 0.f) : 1.f;
                float v = acc[i][j][r] * sc + bv;
                if (Cb) Cb[(size_t)rg * N + col] = f2bf(v);
                else    Cf[(size_t)rg * N + col] = v;
            }
        }
    }
}

// ---------------- CSR aggregation: H[n] = relu(nd[n] * sum_{s in N(n)} T[s] + b) ----------------
// One WAVE per node: 64 lanes x (F/64) elems = full row per load instruction.
// Scalar edge indices; 8 outstanding row loads per iter into 4 fp32 chains.
template <int W32>  // u32 words per lane: 4 (F=512) or 2 (F=256)
struct AggVec;
template <> struct AggVec<4> { using T = uint4; };
template <> struct AggVec<2> { using T = uint2; };

template <int F>
__global__ __launch_bounds__(256) void aggregate_kernel(
    const u16* __restrict__ T, const int* __restrict__ csr,
    const int* __restrict__ offs, const float* __restrict__ nd,
    const float* __restrict__ bias, u16* __restrict__ H) {
    constexpr int W32 = F / 128;  // u32 words per lane
    using VT = typename AggVec<W32>::T;
    const int t = threadIdx.x, w = t >> 6, l = t & 63;
    const int node = blockIdx.x * 4 + w;
    u32* __restrict__ Hrow = (u32*)H + (size_t)node * (F / 2) + l * W32;
    if (node >= N_NODES) {
        VT z = {};
        *(VT*)Hrow = z;
        return;
    }
    const int s0 = __builtin_amdgcn_readfirstlane(offs[node]);
    const int s1 = __builtin_amdgcn_readfirstlane(offs[node + 1]);
    const u32* __restrict__ Tb = (const u32*)T + l * W32;

    float acc[4][2 * W32];
#pragma unroll
    for (int c = 0; c < 4; ++c)
#pragma unroll
        for (int j = 0; j < 2 * W32; ++j) acc[c][j] = 0.f;

    int e = s0;
    for (; e + 8 <= s1; e += 8) {  // 8 loads in flight, 4 accumulator chains
        int si[8];
#pragma unroll
        for (int c = 0; c < 8; ++c) si[c] = csr[e + c];
        VT v[8];
#pragma unroll
        for (int c = 0; c < 8; ++c)
            v[c] = *(const VT*)(Tb + (size_t)si[c] * (F / 2));
#pragma unroll
        for (int c = 0; c < 8; ++c) {
            const u32* vv = (const u32*)&v[c];
#pragma unroll
            for (int j = 0; j < W32; ++j) {
                acc[c & 3][2 * j] += bf2f(vv[j] & 0xffffu);
                acc[c & 3][2 * j + 1] += bf2f(vv[j] >> 16);
            }
        }
    }
    for (; e + 4 <= s1; e += 4) {
        int si[4];
#pragma unroll
        for (int c = 0; c < 4; ++c) si[c] = csr[e + c];
        VT v[4];
#pragma unroll
        for (int c = 0; c < 4; ++c)
            v[c] = *(const VT*)(Tb + (size_t)si[c] * (F / 2));
#pragma unroll
        for (int c = 0; c < 4; ++c) {
            const u32* vv = (const u32*)&v[c];
#pragma unroll
            for (int j = 0; j < W32; ++j) {
                acc[c][2 * j] += bf2f(vv[j] & 0xffffu);
                acc[c][2 * j + 1] += bf2f(vv[j] >> 16);
            }
        }
    }
    for (; e < s1; ++e) {
        int s = csr[e];
        VT v = *(const VT*)(Tb + (size_t)s * (F / 2));
        const u32* vv = (const u32*)&v;
#pragma unroll
        for (int j = 0; j < W32; ++j) {
            acc[0][2 * j] += bf2f(vv[j] & 0xffffu);
            acc[0][2 * j + 1] += bf2f(vv[j] >> 16);
        }
    }

    const float ndv = nd[node];
    u32 ow[W32];
#pragma unroll
    for (int j = 0; j < W32; ++j) {
        float a0 = acc[0][2 * j] + acc[1][2 * j] + acc[2][2 * j] + acc[3][2 * j];
        float a1 = acc[0][2 * j + 1] + acc[1][2 * j + 1] + acc[2][2 * j + 1] + acc[3][2 * j + 1];
        float r0 = fmaxf(fmaf(a0, ndv, bias[l * 2 * W32 + 2 * j]), 0.f);
        float r1 = fmaxf(fmaf(a1, ndv, bias[l * 2 * W32 + 2 * j + 1]), 0.f);
        ow[j] = (u32)f2bf(r0) | ((u32)f2bf(r1) << 16);
    }
    VT o;
    u32* op = (u32*)&o;
#pragma unroll
    for (int j = 0; j < W32; ++j) op[j] = ow[j];
    *(VT*)Hrow = o;
}

// ---------------- launch ----------------

extern "C" void kernel_launch(void* const* d_in, const int* in_sizes, int n_in,
                              void* d_out, int out_size, void* d_ws, size_t ws_size,
                              hipStream_t stream) {
    const float* x   = (const float*)d_in[0];
    const int*   src = (const int*)d_in[1];
    const int*   dst = (const int*)d_in[2];
    const int*   xidx= (const int*)d_in[3];
    const int*   cidx= (const int*)d_in[4];
    const float* W1  = (const float*)d_in[5];
    const float* b1  = (const float*)d_in[6];
    const float* W2  = (const float*)d_in[7];
    const float* b2  = (const float*)d_in[8];
    const float* W3  = (const float*)d_in[9];
    const float* b3  = (const float*)d_in[10];
    const float* Wp  = (const float*)d_in[11];
    const float* bp  = (const float*)d_in[12];
    const float* emb = (const float*)d_in[13];
    float* out = (float*)d_out;

    char* p = (char*)d_ws;
    auto alloc = [&](size_t bytes) {
        char* r = p;
        p += (bytes + 255) & ~(size_t)255;
        return r;
    };
    u16* T    = (u16*)alloc((size_t)MPAD * 512 * 2);   // transformed features (bf16, ns-scaled)
    u16* HX   = (u16*)alloc((size_t)MPAD * 512 * 2);   // x_bf16 / h1 / h2 / h3 (in-place rotate)
    u16* W1T  = (u16*)alloc((size_t)512 * 512 * 2);
    u16* W2T  = (u16*)alloc((size_t)512 * 512 * 2);
    u16* W3T  = (u16*)alloc((size_t)256 * 512 * 2);
    u16* WpT  = (u16*)alloc((size_t)128 * 256 * 2);
    u16* projb= (u16*)alloc((size_t)N_SEL * N_DIM * 2);
    u16* eb   = (u16*)alloc((size_t)N_C * N_DIM * 2);
    int* degO   = (int*)alloc(N_NODES * 4);
    int* degI   = (int*)alloc(N_NODES * 4);
    int* cursor = (int*)alloc(N_NODES * 4);
    int* offs   = (int*)alloc((N_NODES + 1) * 4);
    float* ns   = (float*)alloc(N_NODES * 4);
    float* nd   = (float*)alloc(N_NODES * 4);
    int* csr    = (int*)alloc(N_EDGES * 4);
    int* bsum   = (int*)alloc(SCAN_NB * 4);
    int* boff   = (int*)alloc(SCAN_NB * 4);
    if ((size_t)(p - (char*)d_ws) > ws_size) return;  // scratch too small — bail

    // graph prep
    hipMemsetAsync(degO, 0, (size_t)((char*)offs - (char*)degO), stream);  // degO,degI,cursor
    degrees_kernel<<<(N_EDGES + 255) / 256, 256, 0, stream>>>(src, dst, degO, degI);
    scan_blocksum_kernel<<<SCAN_NB, SCAN_B, 0, stream>>>(degI, bsum);
    scan_bsum_kernel<<<1, SCAN_B, 0, stream>>>(bsum, boff);
    scan_final_kernel<<<SCAN_NB, SCAN_B, 0, stream>>>(degI, boff, offs);
    fill_csr_kernel<<<(N_EDGES + 255) / 256, 256, 0, stream>>>(src, dst, cursor, offs, csr);
    norms_kernel<<<(N_NODES + 255) / 256, 256, 0, stream>>>(degO, degI, ns, nd);

    // weight transposes + input conversion
    trans_bf16_kernel<<<(512 * 512) / 256, 256, 0, stream>>>(W1, W1T, 512, 512);
    trans_bf16_kernel<<<(512 * 512) / 256, 256, 0, stream>>>(W2, W2T, 512, 512);
    trans_bf16_kernel<<<(512 * 256) / 256, 256, 0, stream>>>(W3, W3T, 512, 256);
    trans_bf16_kernel<<<(256 * 128) / 256, 256, 0, stream>>>(Wp, WpT, 256, 128);
    convert_x_kernel<<<(MPAD * 512 / 4) / 256, 256, 0, stream>>>(x, HX);
    gather_emb_kernel<<<N_C, N_DIM, 0, stream>>>(emb, cidx, eb);

    // layer 1: T = (x @ W1) * ns ; h1 = relu(nd * agg(T) + b1)
    gemm_bf16_nt<<<dim3(MPAD / 256, 512 / 128), 512, 0, stream>>>(
        HX, W1T, nullptr, T, nullptr, ns, N_NODES, nullptr, 512, 512);
    aggregate_kernel<512><<<MPAD / 4, 256, 0, stream>>>(T, csr, offs, nd, b1, HX);
    // layer 2
    gemm_bf16_nt<<<dim3(MPAD / 256, 512 / 128), 512, 0, stream>>>(
        HX, W2T, nullptr, T, nullptr, ns, N_NODES, nullptr, 512, 512);
    aggregate_kernel<512><<<MPAD / 4, 256, 0, stream>>>(T, csr, offs, nd, b2, HX);
    // layer 3 (transform-first: aggregate at 256 feats)
    gemm_bf16_nt<<<dim3(MPAD / 256, 256 / 128), 512, 0, stream>>>(
        HX, W3T, nullptr, T, nullptr, ns, N_NODES, nullptr, 256, 512);
    aggregate_kernel<256><<<MPAD / 4, 256, 0, stream>>>(T, csr, offs, nd, b3, HX);

    // proj = h3[x_indices] @ Wp + bp   (A-row gather fused into GEMM staging)
    gemm_bf16_nt<<<dim3(N_SEL / 256, 1), 512, 0, stream>>>(
        HX, WpT, xidx, projb, nullptr, nullptr, 0, bp, N_DIM, 256);
    // out = e @ proj^T   (fp32 output)
    gemm_bf16_nt<<<dim3(N_C / 256, N_SEL / 128), 512, 0, stream>>>(
        eb, projb, nullptr, nullptr, out, nullptr, 0, nullptr, N_SEL, N_DIM);
}

// Round 5
// 601.022 us; speedup vs baseline: 1.3658x; 1.0192x over previous
//
#include <hip/hip_runtime.h>

typedef unsigned int u32;
typedef unsigned short u16;

#define N_NODES 50000
#define N_EDGES 400000
#define IN_F 512
#define HID 512
#define OUT_F 256
#define N_CELL 1000
#define N_DIM 128
#define N_SEL 8192
#define N_C 1024
#define MPAD 50176  // 392*128, node count padded to 128-row GEMM tiles

#define SCAN_B 256
#define SCAN_NB ((N_NODES + SCAN_B - 1) / SCAN_B)  // 196

typedef __bf16 bf16x8 __attribute__((ext_vector_type(8)));
typedef float f32x4 __attribute__((ext_vector_type(4)));

__device__ __forceinline__ u16 f2bf(float f) {
    u32 u = __builtin_bit_cast(u32, f);
    u32 r = (u + 0x7fffu + ((u >> 16) & 1u)) >> 16;  // RNE
    return (u16)r;
}
__device__ __forceinline__ float bf2f(u32 bits16) {
    return __builtin_bit_cast(float, bits16 << 16);
}

// async 16B global -> LDS (dest = wave-uniform base + lane*16)
__device__ __forceinline__ void async_copy16(const u16* g, u16* l) {
    __builtin_amdgcn_global_load_lds(
        (const __attribute__((address_space(1))) void*)g,
        (__attribute__((address_space(3))) void*)l, 16, 0, 0);
}

// ---------------- graph prep ----------------

__global__ void degrees_kernel(const int* __restrict__ src, const int* __restrict__ dst,
                               int* __restrict__ degO, int* __restrict__ degI) {
    int e = blockIdx.x * 256 + threadIdx.x;
    if (e < N_EDGES) {
        atomicAdd(&degO[src[e]], 1);
        atomicAdd(&degI[dst[e]], 1);
    }
}

// --- 3-phase parallel exclusive scan of degI -> offs[0..N_NODES] ---
__global__ void scan_blocksum_kernel(const int* __restrict__ deg, int* __restrict__ bsum) {
    __shared__ int sh[SCAN_B];
    int i = blockIdx.x * SCAN_B + threadIdx.x;
    int v = (i < N_NODES) ? deg[i] : 0;
    sh[threadIdx.x] = v;
    __syncthreads();
    for (int off = SCAN_B / 2; off > 0; off >>= 1) {
        if (threadIdx.x < off) sh[threadIdx.x] += sh[threadIdx.x + off];
        __syncthreads();
    }
    if (threadIdx.x == 0) bsum[blockIdx.x] = sh[0];
}

__global__ void scan_bsum_kernel(const int* __restrict__ bsum, int* __restrict__ boff) {
    __shared__ int sh[SCAN_B];
    const int t = threadIdx.x;
    int v = (t < SCAN_NB) ? bsum[t] : 0;
    sh[t] = v;
    __syncthreads();
    for (int off = 1; off < SCAN_B; off <<= 1) {
        int u = (t >= off) ? sh[t - off] : 0;
        __syncthreads();
        sh[t] += u;
        __syncthreads();
    }
    if (t < SCAN_NB) boff[t] = sh[t] - v;  // exclusive
}

__global__ void scan_final_kernel(const int* __restrict__ deg, const int* __restrict__ boff,
                                  int* __restrict__ offs) {
    __shared__ int sh[SCAN_B];
    const int t = threadIdx.x;
    int i = blockIdx.x * SCAN_B + t;
    int v = (i < N_NODES) ? deg[i] : 0;
    sh[t] = v;
    __syncthreads();
    for (int off = 1; off < SCAN_B; off <<= 1) {
        int u = (t >= off) ? sh[t - off] : 0;
        __syncthreads();
        sh[t] += u;
        __syncthreads();
    }
    if (i < N_NODES) offs[i] = boff[blockIdx.x] + sh[t] - v;
    if (i == 0) offs[N_NODES] = N_EDGES;  // total degree = edge count
}

__global__ void fill_csr_kernel(const int* __restrict__ src, const int* __restrict__ dst,
                                int* __restrict__ cursor, const int* __restrict__ offs,
                                int* __restrict__ csr) {
    int e = blockIdx.x * 256 + threadIdx.x;
    if (e < N_EDGES) {
        int d = dst[e];
        int slot = atomicAdd(&cursor[d], 1);
        csr[offs[d] + slot] = src[e];
    }
}

__global__ void norms_kernel(const int* __restrict__ degO, const int* __restrict__ degI,
                             float* __restrict__ ns, float* __restrict__ nd) {
    int i = blockIdx.x * 256 + threadIdx.x;
    if (i < N_NODES) {
        ns[i] = degO[i] > 0 ? rsqrtf((float)degO[i]) : 0.f;
        nd[i] = degI[i] > 0 ? rsqrtf((float)degI[i]) : 0.f;
    }
}

// ---------------- conversions ----------------

// src[K][N] fp32 -> dst[N][K] bf16 (weights, small)
__global__ void trans_bf16_kernel(const float* __restrict__ src, u16* __restrict__ dst,
                                  int K, int N) {
    int i = blockIdx.x * 256 + threadIdx.x;
    if (i >= K * N) return;
    int n = i / K, k = i % K;
    dst[i] = f2bf(src[k * N + n]);
}

// x fp32 [N_NODES][512] -> bf16 [MPAD][512], zero pad rows
__global__ void convert_x_kernel(const float* __restrict__ x, u16* __restrict__ xb) {
    int i = blockIdx.x * 256 + threadIdx.x;  // one per 4 elems; grid exact
    int base = i * 4;
    int m = base >> 9;
    ushort4 o;
    if (m < N_NODES) {
        float4 v = *(const float4*)(x + base);
        o.x = f2bf(v.x); o.y = f2bf(v.y); o.z = f2bf(v.z); o.w = f2bf(v.w);
    } else {
        o = make_ushort4(0, 0, 0, 0);
    }
    *(ushort4*)(xb + base) = o;
}

// eb[c][:] = bf16(emb[c_indices[c]][:])
__global__ void gather_emb_kernel(const float* __restrict__ emb, const int* __restrict__ cidx,
                                  u16* __restrict__ eb) {
    int c = blockIdx.x, f = threadIdx.x;
    eb[c * N_DIM + f] = f2bf(emb[(size_t)cidx[c] * N_DIM + f]);
}

// ---------------- MFMA GEMM (NT: A[M][K] bf16, B[N][K] bf16) ----------------
// C = A @ B^T ; optional A-row gather (aidx), row scale, col bias; bf16 or f32 out.
// 128x128 tile, 256 threads / 4 waves, wave tile 64x64 (4x4 of 16x16x32).
// DOUBLE-BUFFERED LDS, ONE barrier per K-iter: the DMA for iter k+1 is issued
// immediately after the barrier of iter k into the other buffer, so it has the
// whole MFMA phase in flight before the next barrier's vmcnt(0) drain.
// Staging via global_load_lds width=16; UNPADDED 128x32 LDS layout per buffer
// (wave-uniform base + lane*16 DMA constraint).
__global__ __launch_bounds__(256, 2) void gemm_bf16_nt(
    const u16* __restrict__ A, const u16* __restrict__ B,
    const int* __restrict__ aidx,
    u16* __restrict__ Cb, float* __restrict__ Cf,
    const float* __restrict__ scale, int nScale,
    const float* __restrict__ bias,
    int N, int K) {
    __shared__ __align__(16) u16 As[2 * 4096];  // 2 buffers x 128x32
    __shared__ __align__(16) u16 Bs[2 * 4096];
    const int t = threadIdx.x;
    const int m0 = blockIdx.x * 128, n0 = blockIdx.y * 128;
    const int l = t & 63, w = t >> 6;
    const int wm = (w >> 1) << 6, wn = (w & 1) << 6;
    const int lr = l & 15, quad = l >> 4;

    // staging map: 8 regions of 16 rows; wave w does regions w and w+4.
    // lane i covers (row = region*16 + i/4, kelem = (i&3)*8 .. +8)
    const int lrow = l >> 2;
    const int kof = (l & 3) << 3;
    const int r0 = w, r1 = w + 4;
    int ar0 = m0 + r0 * 16 + lrow;
    int ar1 = m0 + r1 * 16 + lrow;
    if (aidx) { ar0 = aidx[ar0]; ar1 = aidx[ar1]; }
    const u16* gA0 = A + (size_t)ar0 * K + kof;
    const u16* gA1 = A + (size_t)ar1 * K + kof;
    const u16* gB0 = B + (size_t)(n0 + r0 * 16 + lrow) * K + kof;
    const u16* gB1 = B + (size_t)(n0 + r1 * 16 + lrow) * K + kof;
    u16* lA0 = As + r0 * 512;  // wave-uniform LDS bases (buf0; buf1 = +4096)
    u16* lA1 = As + r1 * 512;
    u16* lB0 = Bs + r0 * 512;
    u16* lB1 = Bs + r1 * 512;

    f32x4 acc[4][4] = {};

    // prologue: stage iter 0 into buf0
    async_copy16(gA0, lA0);
    async_copy16(gA1, lA1);
    async_copy16(gB0, lB0);
    async_copy16(gB1, lB1);

    const int niter = K >> 5;
    for (int it = 0; it < niter; ++it) {
        const int cur = (it & 1) << 12;   // 0 / 4096
        const int nxt = 4096 - cur;
        __syncthreads();  // drains DMA into buf[cur]; prior reads of buf[nxt] done
        if (it + 1 < niter) {
            const int ks = (it + 1) << 5;
            async_copy16(gA0 + ks, lA0 + nxt);
            async_copy16(gA1 + ks, lA1 + nxt);
            async_copy16(gB0 + ks, lB0 + nxt);
            async_copy16(gB1 + ks, lB1 + nxt);
        }
        bf16x8 af[4], bg[4];
#pragma unroll
        for (int i = 0; i < 4; ++i)
            af[i] = *(const bf16x8*)&As[cur + (wm + i * 16 + lr) * 32 + quad * 8];
#pragma unroll
        for (int j = 0; j < 4; ++j)
            bg[j] = *(const bf16x8*)&Bs[cur + (wn + j * 16 + lr) * 32 + quad * 8];
#pragma unroll
        for (int i = 0; i < 4; ++i)
#pragma unroll
            for (int j = 0; j < 4; ++j)
                acc[i][j] = __builtin_amdgcn_mfma_f32_16x16x32_bf16(af[i], bg[j], acc[i][j], 0, 0, 0);
    }

    // C/D layout (m89-verified): col = lane&15, row = quad*4 + reg
#pragma unroll
    for (int i = 0; i < 4; ++i) {
        int rbase = m0 + wm + i * 16 + quad * 4;
#pragma unroll
        for (int j = 0; j < 4; ++j) {
            int col = n0 + wn + j * 16 + lr;
            float bv = bias ? bias[col] : 0.f;
#pragma unroll
            for (int r = 0; r < 4; ++r) {
                int rg = rbase + r;
                float sc = scale ? (rg < nScale ? scale[rg] : 0.f) : 1.f;
                float v = acc[i][j][r] * sc + bv;
                if (Cb) Cb[(size_t)rg * N + col] = f2bf(v);
                else    Cf[(size_t)rg * N + col] = v;
            }
        }
    }
}

// ---------------- CSR aggregation: H[n] = relu(nd[n] * sum_{s in N(n)} T[s] + b) ----------------
// One WAVE per node: 64 lanes x (F/64) elems = full row per load instruction.
// Scalar edge indices; 8 outstanding row loads per iter into 4 fp32 chains.
template <int W32>  // u32 words per lane: 4 (F=512) or 2 (F=256)
struct AggVec;
template <> struct AggVec<4> { using T = uint4; };
template <> struct AggVec<2> { using T = uint2; };

template <int F>
__global__ __launch_bounds__(256) void aggregate_kernel(
    const u16* __restrict__ T, const int* __restrict__ csr,
    const int* __restrict__ offs, const float* __restrict__ nd,
    const float* __restrict__ bias, u16* __restrict__ H) {
    constexpr int W32 = F / 128;  // u32 words per lane
    using VT = typename AggVec<W32>::T;
    const int t = threadIdx.x, w = t >> 6, l = t & 63;
    const int node = blockIdx.x * 4 + w;
    u32* __restrict__ Hrow = (u32*)H + (size_t)node * (F / 2) + l * W32;
    if (node >= N_NODES) {
        VT z = {};
        *(VT*)Hrow = z;
        return;
    }
    const int s0 = __builtin_amdgcn_readfirstlane(offs[node]);
    const int s1 = __builtin_amdgcn_readfirstlane(offs[node + 1]);
    const u32* __restrict__ Tb = (const u32*)T + l * W32;

    float acc[4][2 * W32];
#pragma unroll
    for (int c = 0; c < 4; ++c)
#pragma unroll
        for (int j = 0; j < 2 * W32; ++j) acc[c][j] = 0.f;

    int e = s0;
    for (; e + 8 <= s1; e += 8) {  // 8 loads in flight, 4 accumulator chains
        int si[8];
#pragma unroll
        for (int c = 0; c < 8; ++c) si[c] = csr[e + c];
        VT v[8];
#pragma unroll
        for (int c = 0; c < 8; ++c)
            v[c] = *(const VT*)(Tb + (size_t)si[c] * (F / 2));
#pragma unroll
        for (int c = 0; c < 8; ++c) {
            const u32* vv = (const u32*)&v[c];
#pragma unroll
            for (int j = 0; j < W32; ++j) {
                acc[c & 3][2 * j] += bf2f(vv[j] & 0xffffu);
                acc[c & 3][2 * j + 1] += bf2f(vv[j] >> 16);
            }
        }
    }
    for (; e + 4 <= s1; e += 4) {
        int si[4];
#pragma unroll
        for (int c = 0; c < 4; ++c) si[c] = csr[e + c];
        VT v[4];
#pragma unroll
        for (int c = 0; c < 4; ++c)
            v[c] = *(const VT*)(Tb + (size_t)si[c] * (F / 2));
#pragma unroll
        for (int c = 0; c < 4; ++c) {
            const u32* vv = (const u32*)&v[c];
#pragma unroll
            for (int j = 0; j < W32; ++j) {
                acc[c][2 * j] += bf2f(vv[j] & 0xffffu);
                acc[c][2 * j + 1] += bf2f(vv[j] >> 16);
            }
        }
    }
    for (; e < s1; ++e) {
        int s = csr[e];
        VT v = *(const VT*)(Tb + (size_t)s * (F / 2));
        const u32* vv = (const u32*)&v;
#pragma unroll
        for (int j = 0; j < W32; ++j) {
            acc[0][2 * j] += bf2f(vv[j] & 0xffffu);
            acc[0][2 * j + 1] += bf2f(vv[j] >> 16);
        }
    }

    const float ndv = nd[node];
    u32 ow[W32];
#pragma unroll
    for (int j = 0; j < W32; ++j) {
        float a0 = acc[0][2 * j] + acc[1][2 * j] + acc[2][2 * j] + acc[3][2 * j];
        float a1 = acc[0][2 * j + 1] + acc[1][2 * j + 1] + acc[2][2 * j + 1] + acc[3][2 * j + 1];
        float r0 = fmaxf(fmaf(a0, ndv, bias[l * 2 * W32 + 2 * j]), 0.f);
        float r1 = fmaxf(fmaf(a1, ndv, bias[l * 2 * W32 + 2 * j + 1]), 0.f);
        ow[j] = (u32)f2bf(r0) | ((u32)f2bf(r1) << 16);
    }
    VT o;
    u32* op = (u32*)&o;
#pragma unroll
    for (int j = 0; j < W32; ++j) op[j] = ow[j];
    *(VT*)Hrow = o;
}

// ---------------- launch ----------------

extern "C" void kernel_launch(void* const* d_in, const int* in_sizes, int n_in,
                              void* d_out, int out_size, void* d_ws, size_t ws_size,
                              hipStream_t stream) {
    const float* x   = (const float*)d_in[0];
    const int*   src = (const int*)d_in[1];
    const int*   dst = (const int*)d_in[2];
    const int*   xidx= (const int*)d_in[3];
    const int*   cidx= (const int*)d_in[4];
    const float* W1  = (const float*)d_in[5];
    const float* b1  = (const float*)d_in[6];
    const float* W2  = (const float*)d_in[7];
    const float* b2  = (const float*)d_in[8];
    const float* W3  = (const float*)d_in[9];
    const float* b3  = (const float*)d_in[10];
    const float* Wp  = (const float*)d_in[11];
    const float* bp  = (const float*)d_in[12];
    const float* emb = (const float*)d_in[13];
    float* out = (float*)d_out;

    char* p = (char*)d_ws;
    auto alloc = [&](size_t bytes) {
        char* r = p;
        p += (bytes + 255) & ~(size_t)255;
        return r;
    };
    u16* T    = (u16*)alloc((size_t)MPAD * 512 * 2);   // transformed features (bf16, ns-scaled)
    u16* HX   = (u16*)alloc((size_t)MPAD * 512 * 2);   // x_bf16 / h1 / h2 / h3 (in-place rotate)
    u16* W1T  = (u16*)alloc((size_t)512 * 512 * 2);
    u16* W2T  = (u16*)alloc((size_t)512 * 512 * 2);
    u16* W3T  = (u16*)alloc((size_t)256 * 512 * 2);
    u16* WpT  = (u16*)alloc((size_t)128 * 256 * 2);
    u16* projb= (u16*)alloc((size_t)N_SEL * N_DIM * 2);
    u16* eb   = (u16*)alloc((size_t)N_C * N_DIM * 2);
    int* degO   = (int*)alloc(N_NODES * 4);
    int* degI   = (int*)alloc(N_NODES * 4);
    int* cursor = (int*)alloc(N_NODES * 4);
    int* offs   = (int*)alloc((N_NODES + 1) * 4);
    float* ns   = (float*)alloc(N_NODES * 4);
    float* nd   = (float*)alloc(N_NODES * 4);
    int* csr    = (int*)alloc(N_EDGES * 4);
    int* bsum   = (int*)alloc(SCAN_NB * 4);
    int* boff   = (int*)alloc(SCAN_NB * 4);
    if ((size_t)(p - (char*)d_ws) > ws_size) return;  // scratch too small — bail

    // graph prep
    hipMemsetAsync(degO, 0, (size_t)((char*)offs - (char*)degO), stream);  // degO,degI,cursor
    degrees_kernel<<<(N_EDGES + 255) / 256, 256, 0, stream>>>(src, dst, degO, degI);
    scan_blocksum_kernel<<<SCAN_NB, SCAN_B, 0, stream>>>(degI, bsum);
    scan_bsum_kernel<<<1, SCAN_B, 0, stream>>>(bsum, boff);
    scan_final_kernel<<<SCAN_NB, SCAN_B, 0, stream>>>(degI, boff, offs);
    fill_csr_kernel<<<(N_EDGES + 255) / 256, 256, 0, stream>>>(src, dst, cursor, offs, csr);
    norms_kernel<<<(N_NODES + 255) / 256, 256, 0, stream>>>(degO, degI, ns, nd);

    // weight transposes + input conversion
    trans_bf16_kernel<<<(512 * 512) / 256, 256, 0, stream>>>(W1, W1T, 512, 512);
    trans_bf16_kernel<<<(512 * 512) / 256, 256, 0, stream>>>(W2, W2T, 512, 512);
    trans_bf16_kernel<<<(512 * 256) / 256, 256, 0, stream>>>(W3, W3T, 512, 256);
    trans_bf16_kernel<<<(256 * 128) / 256, 256, 0, stream>>>(Wp, WpT, 256, 128);
    convert_x_kernel<<<(MPAD * 512 / 4) / 256, 256, 0, stream>>>(x, HX);
    gather_emb_kernel<<<N_C, N_DIM, 0, stream>>>(emb, cidx, eb);

    // layer 1: T = (x @ W1) * ns ; h1 = relu(nd * agg(T) + b1)
    gemm_bf16_nt<<<dim3(MPAD / 128, 512 / 128), 256, 0, stream>>>(
        HX, W1T, nullptr, T, nullptr, ns, N_NODES, nullptr, 512, 512);
    aggregate_kernel<512><<<MPAD / 4, 256, 0, stream>>>(T, csr, offs, nd, b1, HX);
    // layer 2
    gemm_bf16_nt<<<dim3(MPAD / 128, 512 / 128), 256, 0, stream>>>(
        HX, W2T, nullptr, T, nullptr, ns, N_NODES, nullptr, 512, 512);
    aggregate_kernel<512><<<MPAD / 4, 256, 0, stream>>>(T, csr, offs, nd, b2, HX);
    // layer 3 (transform-first: aggregate at 256 feats)
    gemm_bf16_nt<<<dim3(MPAD / 128, 256 / 128), 256, 0, stream>>>(
        HX, W3T, nullptr, T, nullptr, ns, N_NODES, nullptr, 256, 512);
    aggregate_kernel<256><<<MPAD / 4, 256, 0, stream>>>(T, csr, offs, nd, b3, HX);

    // proj = h3[x_indices] @ Wp + bp   (A-row gather fused into GEMM staging)
    gemm_bf16_nt<<<dim3(N_SEL / 128, 1), 256, 0, stream>>>(
        HX, WpT, xidx, projb, nullptr, nullptr, 0, bp, N_DIM, 256);
    // out = e @ proj^T   (fp32 output)
    gemm_bf16_nt<<<dim3(N_C / 128, N_SEL / 128), 256, 0, stream>>>(
        eb, projb, nullptr, nullptr, out, nullptr, 0, nullptr, N_SEL, N_DIM);
}